// Round 9
// baseline (123.859 us; speedup 1.0000x reference)
//
#include <hip/hip_runtime.h>
#include <math.h>

#define KNN 16
#define DIM 128
#define BQ 256
#define NDB 100000
#define NC 128                   // db rows per block
#define NBLK 782                 // ceil(100000/128)
#define RPP 32                   // rows per phase
#define NPH (NC / RPP)           // 4
#define XB_STR 136               // ushorts per LDS B-row (128 + 8 pad)
#define CAP 4096                 // per-query candidate capacity (generous; expected ~25)
#define MREG 13                  // ceil(NBLK/64)
#define TAU_INV 10.0f
#define EPSC 1e-8f
#define FBIG 3.402823e38f

typedef float f32x4 __attribute__((ext_vector_type(4)));
typedef __bf16 bf16x8 __attribute__((ext_vector_type(8)));
typedef unsigned short ushort;
typedef ushort ushort8 __attribute__((ext_vector_type(8)));

__device__ __forceinline__ ushort f32_to_bf16_rne(float v) {
    unsigned bits = __float_as_uint(v);
    return (ushort)((bits + 0x7FFFu + ((bits >> 16) & 1u)) >> 16);
}

// ---------------- Kernel A: Tq = q_batch @ W (f32 + bf16 copies) ----------------
__global__ void k_tq(const float* __restrict__ qb, const float* __restrict__ W,
                     float* __restrict__ Tq, ushort* __restrict__ Tqb) {
    int b = blockIdx.x, c = threadIdx.x;   // 128 threads
    __shared__ float qs[DIM];
    qs[c] = qb[b * DIM + c];
    __syncthreads();
    float acc = 0.f;
#pragma unroll 8
    for (int k = 0; k < DIM; ++k) acc = fmaf(qs[k], W[k * DIM + c], acc);
    Tq[b * DIM + c] = acc;
    Tqb[b * DIM + c] = f32_to_bf16_rne(acc);
}

// ---------------- Kernel B: MFMA distance pass (runtime mode => identical code both passes) ----
// mode 0: per-(block,query) min -> blkmin[blk][q]
// mode 1: recompute (bit-identical); append (v, j) with v <= tau_eff[q] to cand[q][*]
__global__ __launch_bounds__(256, 2)
void k_pass(const int mode, const ushort* __restrict__ Tqb, const float* __restrict__ X,
            float* __restrict__ blkmin, const float* __restrict__ tau,
            float2* __restrict__ cand, int* __restrict__ cnt) {
    __shared__ ushort xb[2][RPP * XB_STR];   // 2 x 8.5KB bf16 tiles (padded rows)
    __shared__ float xsq_lds[2][RPP];
    __shared__ float tau_lds[BQ];
    const int t = threadIdx.x;
    const int w = t >> 6;          // wave -> queries [64w, 64w+64)
    const int lane = t & 63;
    const int la = lane >> 4;      // 0..3
    const int lb = lane & 15;      // 0..15
    const int sr = t >> 3;         // staged row 0..31
    const int sc = t & 7;          // staged 16-dim chunk 0..7
    const int j0 = blockIdx.x * NC;

    // A fragments: 64 queries x K=128 (row = lane&15, k = (lane>>4)*8 + ks*32)
    bf16x8 afr[4][4];
#pragma unroll
    for (int mt = 0; mt < 4; ++mt)
#pragma unroll
        for (int ks = 0; ks < 4; ++ks)
            afr[mt][ks] = *reinterpret_cast<const bf16x8*>(
                Tqb + (size_t)(w * 64 + mt * 16 + lb) * DIM + ks * 32 + la * 8);

    tau_lds[t] = (mode == 1) ? tau[t] : FBIG;

    {   // prolog: stage tile 0 (f32 -> bf16 + xsq)
        int j = j0 + sr; int jc = (j < NDB) ? j : (NDB - 1);
        const float4* src = reinterpret_cast<const float4*>(X + (size_t)jc * DIM + sc * 16);
        float4 v0 = src[0], v1 = src[1], v2 = src[2], v3 = src[3];
        ushort8 o0, o1;
        o0[0]=f32_to_bf16_rne(v0.x); o0[1]=f32_to_bf16_rne(v0.y); o0[2]=f32_to_bf16_rne(v0.z); o0[3]=f32_to_bf16_rne(v0.w);
        o0[4]=f32_to_bf16_rne(v1.x); o0[5]=f32_to_bf16_rne(v1.y); o0[6]=f32_to_bf16_rne(v1.z); o0[7]=f32_to_bf16_rne(v1.w);
        o1[0]=f32_to_bf16_rne(v2.x); o1[1]=f32_to_bf16_rne(v2.y); o1[2]=f32_to_bf16_rne(v2.z); o1[3]=f32_to_bf16_rne(v2.w);
        o1[4]=f32_to_bf16_rne(v3.x); o1[5]=f32_to_bf16_rne(v3.y); o1[6]=f32_to_bf16_rne(v3.z); o1[7]=f32_to_bf16_rne(v3.w);
        *reinterpret_cast<ushort8*>(&xb[0][sr * XB_STR + sc * 16]) = o0;
        *reinterpret_cast<ushort8*>(&xb[0][sr * XB_STR + sc * 16 + 8]) = o1;
        float s = v0.x*v0.x + v0.y*v0.y + v0.z*v0.z + v0.w*v0.w
                + v1.x*v1.x + v1.y*v1.y + v1.z*v1.z + v1.w*v1.w
                + v2.x*v2.x + v2.y*v2.y + v2.z*v2.z + v2.w*v2.w
                + v3.x*v3.x + v3.y*v3.y + v3.z*v3.z + v3.w*v3.w;
        s += __shfl_xor(s, 1, 8); s += __shfl_xor(s, 2, 8); s += __shfl_xor(s, 4, 8);
        if (sc == 0) xsq_lds[0][sr] = s;
    }
    asm volatile("s_waitcnt lgkmcnt(0)" ::: "memory");
    __builtin_amdgcn_s_barrier();            // tile 0 + tau_lds visible

    float taur[4][4];
#pragma unroll
    for (int mt = 0; mt < 4; ++mt)
#pragma unroll
        for (int r = 0; r < 4; ++r)
            taur[mt][r] = tau_lds[w * 64 + mt * 16 + la * 4 + r];
    float runmin[4][4];
#pragma unroll
    for (int mt = 0; mt < 4; ++mt)
#pragma unroll
        for (int r = 0; r < 4; ++r) runmin[mt][r] = FBIG;

#pragma unroll 1
    for (int ph = 0; ph < NPH; ++ph) {
        const int cur = ph & 1, nxt = cur ^ 1;
        const int rbase = j0 + ph * RPP;
        float4 p0, p1, p2, p3;
        if (ph + 1 < NPH) {   // prefetch next tile into regs
            int j = rbase + RPP + sr; int jc = (j < NDB) ? j : (NDB - 1);
            const float4* src = reinterpret_cast<const float4*>(X + (size_t)jc * DIM + sc * 16);
            p0 = src[0]; p1 = src[1]; p2 = src[2]; p3 = src[3];
        }
        asm volatile("s_waitcnt lgkmcnt(0)" ::: "memory");
        __builtin_amdgcn_s_barrier();        // xb[cur]/xsq[cur] ready; xb[nxt] free

#pragma unroll
        for (int nt = 0; nt < 2; ++nt) {
            const int row = nt * 16 + lb;
            bf16x8 bfr[4];
#pragma unroll
            for (int ks = 0; ks < 4; ++ks)
                bfr[ks] = *reinterpret_cast<const bf16x8*>(
                    &xb[cur][row * XB_STR + ks * 32 + la * 8]);
            const float xs = xsq_lds[cur][row];
            const int j = rbase + row;
            const bool oob = (j >= NDB);
#pragma unroll
            for (int mt = 0; mt < 4; ++mt) {
                f32x4 acc = {0.f, 0.f, 0.f, 0.f};
#pragma unroll
                for (int ks = 0; ks < 4; ++ks)
                    acc = __builtin_amdgcn_mfma_f32_16x16x32_bf16(afr[mt][ks], bfr[ks], acc, 0, 0, 0);
#pragma unroll
                for (int r = 0; r < 4; ++r) {
                    float v = oob ? FBIG : (xs - 2.f * acc[r]);
                    if (mode == 0) {
                        runmin[mt][r] = fminf(runmin[mt][r], v);
                    } else if (v <= taur[mt][r]) {   // ~25 hits per query over whole grid
                        int qid = w * 64 + mt * 16 + la * 4 + r;
                        int pos = atomicAdd(&cnt[qid], 1);
                        if (pos < CAP)
                            cand[(size_t)qid * CAP + pos] = make_float2(v, __int_as_float(j));
                    }
                }
            }
        }

        if (ph + 1 < NPH) {                  // write-late staging of next tile
            ushort8 o0, o1;
            o0[0]=f32_to_bf16_rne(p0.x); o0[1]=f32_to_bf16_rne(p0.y); o0[2]=f32_to_bf16_rne(p0.z); o0[3]=f32_to_bf16_rne(p0.w);
            o0[4]=f32_to_bf16_rne(p1.x); o0[5]=f32_to_bf16_rne(p1.y); o0[6]=f32_to_bf16_rne(p1.z); o0[7]=f32_to_bf16_rne(p1.w);
            o1[0]=f32_to_bf16_rne(p2.x); o1[1]=f32_to_bf16_rne(p2.y); o1[2]=f32_to_bf16_rne(p2.z); o1[3]=f32_to_bf16_rne(p2.w);
            o1[4]=f32_to_bf16_rne(p3.x); o1[5]=f32_to_bf16_rne(p3.y); o1[6]=f32_to_bf16_rne(p3.z); o1[7]=f32_to_bf16_rne(p3.w);
            *reinterpret_cast<ushort8*>(&xb[nxt][sr * XB_STR + sc * 16]) = o0;
            *reinterpret_cast<ushort8*>(&xb[nxt][sr * XB_STR + sc * 16 + 8]) = o1;
            float s = p0.x*p0.x + p0.y*p0.y + p0.z*p0.z + p0.w*p0.w
                    + p1.x*p1.x + p1.y*p1.y + p1.z*p1.z + p1.w*p1.w
                    + p2.x*p2.x + p2.y*p2.y + p2.z*p2.z + p2.w*p2.w
                    + p3.x*p3.x + p3.y*p3.y + p3.z*p3.z + p3.w*p3.w;
            s += __shfl_xor(s, 1, 8); s += __shfl_xor(s, 2, 8); s += __shfl_xor(s, 4, 8);
            if (sc == 0) xsq_lds[nxt][sr] = s;
        }
    }

    if (mode == 0) {   // cross-lane min over the 16 db cols, write blkmin[blk][q]
#pragma unroll
        for (int mt = 0; mt < 4; ++mt)
#pragma unroll
            for (int r = 0; r < 4; ++r) {
                float m = runmin[mt][r];
                m = fminf(m, __shfl_xor(m, 1, 16));
                m = fminf(m, __shfl_xor(m, 2, 16));
                m = fminf(m, __shfl_xor(m, 4, 16));
                m = fminf(m, __shfl_xor(m, 8, 16));
                if (lb == 0)
                    blkmin[(size_t)blockIdx.x * BQ + w * 64 + mt * 16 + la * 4 + r] = m;
            }
    }
}

// ---------------- Kernel C: per-query 16th-smallest block min (+slack) -> tau; zero counters ----
__global__ void k_tau(const float* __restrict__ blkmin, float* __restrict__ tau,
                      int* __restrict__ cnt) {
    const int q = blockIdx.x, lane = threadIdx.x;   // 64 threads
    float m[MREG];
#pragma unroll
    for (int k = 0; k < MREG; ++k) {
        int i = lane + (k << 6);
        m[k] = (i < NBLK) ? blkmin[(size_t)i * BQ + q] : FBIG;
    }
    float tv = FBIG;
    for (int e = 0; e < KNN; ++e) {
        float best = m[0];
#pragma unroll
        for (int k = 1; k < MREG; ++k) best = fminf(best, m[k]);
        float b = best;
#pragma unroll
        for (int s = 1; s < 64; s <<= 1) b = fminf(b, __shfl_xor(b, s, 64));
        tv = b;
        unsigned long long has = __ballot(best == b);
        int src = (int)__builtin_ctzll(has);
        if (lane == src) {   // remove exactly one instance
            bool done = false;
#pragma unroll
            for (int k = 0; k < MREG; ++k) {
                bool hit = !done && (m[k] == b);
                if (hit) { m[k] = FBIG; done = true; }
            }
        }
    }
    // slack: robust upper bound on the true 16th distance (absorbs any FP jitter)
    if (lane == 0) { tau[q] = tv * 1.000001f + 1e-3f; cnt[q] = 0; }
}

// ---------------- Kernel D: rank select 16 + exact l2 + softmax + union KL ----------------
__global__ __launch_bounds__(256)
void k_sel(const float2* __restrict__ cand, const int* __restrict__ cnt,
           const float* __restrict__ Tq, const float* __restrict__ X,
           const int* __restrict__ q_indices,
           const int* __restrict__ pre_indices,
           const float* __restrict__ pre_weights,
           float* __restrict__ kl_out) {
    const int q = blockIdx.x, t = threadIdx.x;
    __shared__ float cv[CAP]; __shared__ int cidx[CAP];
    __shared__ int post_idx[KNN];
    __shared__ float l2s[KNN];
    __shared__ float post_w[KNN];
    __shared__ int u_idx[2 * KNN]; __shared__ float u_p[2 * KNN]; __shared__ float u_q[2 * KNN];

    if (t < KNN) post_idx[t] = 0;            // defensive: never leave garbage indices
    int n = cnt[q];
    n = (n < 0) ? 0 : ((n > CAP) ? CAP : n);
    for (int e = t; e < n; e += 256) {
        float2 c = cand[(size_t)q * CAP + e];
        cv[e] = c.x; cidx[e] = __float_as_int(c.y);
    }
    __syncthreads();

    // exact rank select of 16 smallest ((val, idx) total order; append-order invariant)
    for (int e = t; e < n; e += 256) {
        float v = cv[e]; int id = cidx[e];
        int r = 0;
        for (int i2 = 0; i2 < n; ++i2) {
            float vi = cv[i2];
            r += (vi < v) || (vi == v && cidx[i2] < id);
        }
        if (r < KNN) post_idx[r] = id;
    }
    __syncthreads();

    {   // exact f32 l2 for the selected 16 (16 threads x 8 dims each)
        int nn = t >> 4, l = t & 15;
        int idx = post_idx[nn];
        idx = (idx < 0) ? 0 : ((idx >= NDB) ? NDB - 1 : idx);   // defensive clamp
        const float* tr = Tq + q * DIM + l * 8;
        const float* xr = X + (size_t)idx * DIM + l * 8;
        float s = 0.f;
#pragma unroll
        for (int kk = 0; kk < 8; ++kk) { float df = tr[kk] - xr[kk]; s = fmaf(df, df, s); }
#pragma unroll
        for (int m = 1; m < 16; m <<= 1) s += __shfl_xor(s, m, 64);
        if (l == 0) l2s[nn] = s;
    }
    __syncthreads();

    if (t == 0) {
        float mx = -FBIG;
        for (int i = 0; i < KNN; ++i) { float v = -l2s[i] * TAU_INV; post_w[i] = v; if (v > mx) mx = v; }
        float sum = 0.f;
        for (int i = 0; i < KNN; ++i) { float e = expf(post_w[i] - mx); post_w[i] = e; sum += e; }
        float inv = 1.f / sum;
        for (int i = 0; i < KNN; ++i) post_w[i] *= inv;

        int qi = q_indices[q];
        int cnt2 = KNN;
        for (int i = 0; i < KNN; ++i) { u_idx[i] = post_idx[i]; u_q[i] = post_w[i]; u_p[i] = 0.f; }
        for (int m = 0; m < KNN; ++m) {
            int pi = pre_indices[qi * KNN + m];
            float pwm = pre_weights[qi * KNN + m];
            int f = -1;
            for (int s2 = 0; s2 < cnt2; ++s2) if (u_idx[s2] == pi) { f = s2; break; }
            if (f >= 0) u_p[f] = pwm;
            else { u_idx[cnt2] = pi; u_p[cnt2] = pwm; u_q[cnt2] = 0.f; ++cnt2; }
        }
        float Zp = 0.f, Zq = 0.f;
        for (int s2 = 0; s2 < cnt2; ++s2) { Zp += fmaxf(u_p[s2], EPSC); Zq += fmaxf(u_q[s2], EPSC); }
        float kl = 0.f;
        float izp = 1.f / Zp, izq = 1.f / Zq;
        for (int s2 = 0; s2 < cnt2; ++s2) {
            float pp = fmaxf(u_p[s2], EPSC) * izp;
            float qv = fmaxf(u_q[s2], EPSC) * izq;
            kl += pp * (logf(pp) - logf(qv));
        }
        kl_out[q] = kl;
    }
}

// ---------------- Kernel E: final reduction + outputs ----------------
__global__ void k_out(const float* __restrict__ kl, const float* __restrict__ W,
                      float* __restrict__ out) {
    int t = threadIdx.x;
    float s_kl = (t < BQ) ? kl[t] : 0.f;
    float s_w = 0.f;
    for (int i = t; i < DIM * DIM; i += 256) { float w = W[i]; s_w = fmaf(w, w, s_w); }
#pragma unroll
    for (int m = 32; m >= 1; m >>= 1) {
        s_kl += __shfl_xor(s_kl, m, 64);
        s_w += __shfl_xor(s_w, m, 64);
    }
    __shared__ float rk[4], rw[4];
    if ((t & 63) == 0) { rk[t >> 6] = s_kl; rw[t >> 6] = s_w; }
    __syncthreads();
    if (t == 0) {
        float kls = rk[0] + rk[1] + rk[2] + rk[3];
        float wss = rw[0] + rw[1] + rw[2] + rw[3];
        float knn = kls * (1.0f / BQ);
        float reg = 0.5f * wss;
        out[0] = 1.0f * knn + 1e-4f * reg;
        out[1] = 0.f;
        out[2] = knn;
    }
}

extern "C" void kernel_launch(void* const* d_in, const int* in_sizes, int n_in,
                              void* d_out, int out_size, void* d_ws, size_t ws_size,
                              hipStream_t stream) {
    const float* q_batch     = (const float*)d_in[0];
    const int*   q_indices   = (const int*)d_in[1];
    const float* X           = (const float*)d_in[2];
    const float* W           = (const float*)d_in[3];
    const int*   pre_indices = (const int*)d_in[4];
    const float* pre_weights = (const float*)d_in[5];

    char* ws = (char*)d_ws;
    float*  Tq     = (float*)(ws);                  // 128KB
    ushort* Tqb    = (ushort*)(ws + 131072);        // 64KB
    float*  klv    = (float*)(ws + 196608);         // 1KB
    float*  tauv   = (float*)(ws + 197632);         // 1KB
    int*    cntv   = (int*)(ws + 198656);           // 1KB
    float*  blkmin = (float*)(ws + 262144);         // 782*256*4 = 800KB
    float2* cand   = (float2*)(ws + 2097152);       // 256*4096*8 = 8MB

    k_tq<<<dim3(BQ), dim3(DIM), 0, stream>>>(q_batch, W, Tq, Tqb);
    k_pass<<<dim3(NBLK), dim3(256), 0, stream>>>(0, Tqb, X, blkmin, tauv, cand, cntv);
    k_tau<<<dim3(BQ), dim3(64), 0, stream>>>(blkmin, tauv, cntv);
    k_pass<<<dim3(NBLK), dim3(256), 0, stream>>>(1, Tqb, X, blkmin, tauv, cand, cntv);
    k_sel<<<dim3(BQ), dim3(256), 0, stream>>>(cand, cntv, Tq, X,
                                              q_indices, pre_indices, pre_weights, klv);
    k_out<<<dim3(1), dim3(256), 0, stream>>>(klv, W, (float*)d_out);
}

// Round 10
// 96.607 us; speedup vs baseline: 1.2821x; 1.2821x over previous
//
#include <hip/hip_runtime.h>
#include <math.h>

#define KNN 16
#define DIM 128
#define BQ 256
#define NDB 100000
#define GRID 512                 // k_pass blocks (exactly 2 per CU)
#define RPP 32                   // rows per phase-chunk
#define NCHUNK 3125              // 100000 / 32, exact
#define LONGB 53                 // NCHUNK - 6*GRID: blocks with 7 phases
#define XB_STR 136               // ushorts per LDS B-row (128 + 8 pad)
#define CAP 4096                 // per-query candidate capacity (bound: 17 groups * 195 < CAP)
#define MREG 8                   // GRID / 64
#define TAU_INV 10.0f
#define EPSC 1e-8f
#define FBIG 3.402823e38f

typedef float f32x4 __attribute__((ext_vector_type(4)));
typedef __bf16 bf16x8 __attribute__((ext_vector_type(8)));
typedef unsigned short ushort;
typedef ushort ushort8 __attribute__((ext_vector_type(8)));

__device__ __forceinline__ ushort f32_to_bf16_rne(float v) {
    unsigned bits = __float_as_uint(v);
    return (ushort)((bits + 0x7FFFu + ((bits >> 16) & 1u)) >> 16);
}

// ---------------- Kernel A: Tq = q_batch @ W (f32 + bf16 copies) ----------------
__global__ void k_tq(const float* __restrict__ qb, const float* __restrict__ W,
                     float* __restrict__ Tq, ushort* __restrict__ Tqb) {
    int b = blockIdx.x, c = threadIdx.x;   // 128 threads
    __shared__ float qs[DIM];
    qs[c] = qb[b * DIM + c];
    __syncthreads();
    float acc = 0.f;
#pragma unroll 8
    for (int k = 0; k < DIM; ++k) acc = fmaf(qs[k], W[k * DIM + c], acc);
    Tq[b * DIM + c] = acc;
    Tqb[b * DIM + c] = f32_to_bf16_rne(acc);
}

// ---------------- Kernel B: MFMA distance pass (8 waves, A resident: 32 VGPRs) ----------
// mode 0: per-(block,query) running min -> blkmin[bid][q]
// mode 1: recompute (identical code => bit-identical); append (v, j) with v <= tau[q]
__global__ __launch_bounds__(512, 4)
void k_pass(const int mode, const ushort* __restrict__ Tqb, const float* __restrict__ X,
            float* __restrict__ blkmin, const float* __restrict__ tau,
            float2* __restrict__ cand, int* __restrict__ cnt) {
    __shared__ ushort xb[2][RPP * XB_STR];   // 2 x 8.5KB bf16 tiles (padded rows)
    __shared__ float xsq_lds[2][RPP];
    __shared__ float tau_lds[BQ];
    const int t = threadIdx.x;
    const int w = t >> 6;          // wave 0..7 -> queries [32w, 32w+32)
    const int lane = t & 63;
    const int la = lane >> 4;      // 0..3
    const int lb = lane & 15;      // 0..15
    const int sr = t >> 4;         // staged row 0..31
    const int sc = t & 15;         // staged 8-dim chunk 0..15
    const int bid = blockIdx.x;
    const int nph = (bid < LONGB) ? 7 : 6;

    // A fragments: 32 queries x K=128 -> 8 frags = 32 VGPRs (resident)
    bf16x8 afr[2][4];
#pragma unroll
    for (int mt = 0; mt < 2; ++mt)
#pragma unroll
        for (int ks = 0; ks < 4; ++ks)
            afr[mt][ks] = *reinterpret_cast<const bf16x8*>(
                Tqb + (size_t)(w * 32 + mt * 16 + lb) * DIM + ks * 32 + la * 8);

    if (t < BQ) tau_lds[t] = (mode == 1) ? tau[t] : FBIG;

    {   // prolog: stage chunk 0 (f32 -> bf16 + xsq); 32B/thread
        const int rbase = bid * RPP;
        const float4* src = reinterpret_cast<const float4*>(X + (size_t)(rbase + sr) * DIM + sc * 8);
        float4 v0 = src[0], v1 = src[1];
        ushort8 o;
        o[0]=f32_to_bf16_rne(v0.x); o[1]=f32_to_bf16_rne(v0.y); o[2]=f32_to_bf16_rne(v0.z); o[3]=f32_to_bf16_rne(v0.w);
        o[4]=f32_to_bf16_rne(v1.x); o[5]=f32_to_bf16_rne(v1.y); o[6]=f32_to_bf16_rne(v1.z); o[7]=f32_to_bf16_rne(v1.w);
        *reinterpret_cast<ushort8*>(&xb[0][sr * XB_STR + sc * 8]) = o;
        float s = v0.x*v0.x + v0.y*v0.y + v0.z*v0.z + v0.w*v0.w
                + v1.x*v1.x + v1.y*v1.y + v1.z*v1.z + v1.w*v1.w;
        s += __shfl_xor(s, 1, 16); s += __shfl_xor(s, 2, 16);
        s += __shfl_xor(s, 4, 16); s += __shfl_xor(s, 8, 16);
        if (sc == 0) xsq_lds[0][sr] = s;
    }
    asm volatile("s_waitcnt lgkmcnt(0)" ::: "memory");
    __builtin_amdgcn_s_barrier();            // tile 0 + tau_lds visible

    float taur[2][4];
#pragma unroll
    for (int mt = 0; mt < 2; ++mt)
#pragma unroll
        for (int r = 0; r < 4; ++r)
            taur[mt][r] = tau_lds[w * 32 + mt * 16 + la * 4 + r];
    float runmin[2][4];
#pragma unroll
    for (int mt = 0; mt < 2; ++mt)
#pragma unroll
        for (int r = 0; r < 4; ++r) runmin[mt][r] = FBIG;

#pragma unroll 1
    for (int p = 0; p < nph; ++p) {
        const int cur = p & 1, nxt = cur ^ 1;
        const int rbase = (bid + (p << 9)) << 5;      // (bid + 512p)*32, always < 100000
        float4 q0, q1;
        if (p + 1 < nph) {   // prefetch next chunk into regs (hidden under this phase)
            const int rb2 = (bid + ((p + 1) << 9)) << 5;
            const float4* s2 = reinterpret_cast<const float4*>(X + (size_t)(rb2 + sr) * DIM + sc * 8);
            q0 = s2[0]; q1 = s2[1];
        }

#pragma unroll
        for (int nt = 0; nt < 2; ++nt) {
            const int row = nt * 16 + lb;
            bf16x8 bfr[4];
#pragma unroll
            for (int ks = 0; ks < 4; ++ks)
                bfr[ks] = *reinterpret_cast<const bf16x8*>(
                    &xb[cur][row * XB_STR + ks * 32 + la * 8]);
            const float xs = xsq_lds[cur][row];
            const int j = rbase + row;
#pragma unroll
            for (int mt = 0; mt < 2; ++mt) {
                f32x4 acc = {0.f, 0.f, 0.f, 0.f};
#pragma unroll
                for (int ks = 0; ks < 4; ++ks)
                    acc = __builtin_amdgcn_mfma_f32_16x16x32_bf16(afr[mt][ks], bfr[ks], acc, 0, 0, 0);
#pragma unroll
                for (int r = 0; r < 4; ++r) {
                    float v = xs - 2.f * acc[r];
                    if (mode == 0) {
                        runmin[mt][r] = fminf(runmin[mt][r], v);
                    } else if (v <= taur[mt][r]) {   // rare (~40 hits/query total)
                        int qid = w * 32 + mt * 16 + la * 4 + r;
                        int pos = atomicAdd(&cnt[qid], 1);
                        if (pos < CAP)
                            cand[(size_t)qid * CAP + pos] = make_float2(v, __int_as_float(j));
                    }
                }
            }
        }

        if (p + 1 < nph) {   // write-late: convert + stage next tile
            ushort8 o;
            o[0]=f32_to_bf16_rne(q0.x); o[1]=f32_to_bf16_rne(q0.y); o[2]=f32_to_bf16_rne(q0.z); o[3]=f32_to_bf16_rne(q0.w);
            o[4]=f32_to_bf16_rne(q1.x); o[5]=f32_to_bf16_rne(q1.y); o[6]=f32_to_bf16_rne(q1.z); o[7]=f32_to_bf16_rne(q1.w);
            *reinterpret_cast<ushort8*>(&xb[nxt][sr * XB_STR + sc * 8]) = o;
            float s = q0.x*q0.x + q0.y*q0.y + q0.z*q0.z + q0.w*q0.w
                    + q1.x*q1.x + q1.y*q1.y + q1.z*q1.z + q1.w*q1.w;
            s += __shfl_xor(s, 1, 16); s += __shfl_xor(s, 2, 16);
            s += __shfl_xor(s, 4, 16); s += __shfl_xor(s, 8, 16);
            if (sc == 0) xsq_lds[nxt][sr] = s;
            asm volatile("s_waitcnt lgkmcnt(0)" ::: "memory");
            __builtin_amdgcn_s_barrier();    // next tile visible; prev reads all done
        }
    }

    if (mode == 0) {   // cross-lane min over the 16 db cols -> blkmin[bid][q]
#pragma unroll
        for (int mt = 0; mt < 2; ++mt)
#pragma unroll
            for (int r = 0; r < 4; ++r) {
                float m = runmin[mt][r];
                m = fminf(m, __shfl_xor(m, 1, 16));
                m = fminf(m, __shfl_xor(m, 2, 16));
                m = fminf(m, __shfl_xor(m, 4, 16));
                m = fminf(m, __shfl_xor(m, 8, 16));
                if (lb == 0)
                    blkmin[(size_t)bid * BQ + w * 32 + mt * 16 + la * 4 + r] = m;
            }
    }
}

// ---------------- Kernel C: per-query 16th-smallest group min (+slack) -> tau; zero counters ----
__global__ void k_tau(const float* __restrict__ blkmin, float* __restrict__ tau,
                      int* __restrict__ cnt) {
    const int q = blockIdx.x, lane = threadIdx.x;   // 64 threads
    float m[MREG];
#pragma unroll
    for (int k = 0; k < MREG; ++k) {
        int i = lane + (k << 6);                    // i < 512 always
        m[k] = blkmin[(size_t)i * BQ + q];
    }
    float tv = FBIG;
    for (int e = 0; e < KNN; ++e) {
        float best = m[0];
#pragma unroll
        for (int k = 1; k < MREG; ++k) best = fminf(best, m[k]);
        float b = best;
#pragma unroll
        for (int s = 1; s < 64; s <<= 1) b = fminf(b, __shfl_xor(b, s, 64));
        tv = b;
        unsigned long long has = __ballot(best == b);
        int src = (int)__builtin_ctzll(has);
        if (lane == src) {   // remove exactly one instance
            bool done = false;
#pragma unroll
            for (int k = 0; k < MREG; ++k) {
                bool hit = !done && (m[k] == b);
                if (hit) { m[k] = FBIG; done = true; }
            }
        }
    }
    // slack: robust upper bound on the true 16th distance (absorbs any FP jitter)
    if (lane == 0) { tau[q] = tv * 1.000001f + 1e-3f; cnt[q] = 0; }
}

// ---------------- Kernel D: rank select 16 + exact l2 + softmax + union KL ----------------
__global__ __launch_bounds__(256)
void k_sel(const float2* __restrict__ cand, const int* __restrict__ cnt,
           const float* __restrict__ Tq, const float* __restrict__ X,
           const int* __restrict__ q_indices,
           const int* __restrict__ pre_indices,
           const float* __restrict__ pre_weights,
           float* __restrict__ kl_out) {
    const int q = blockIdx.x, t = threadIdx.x;
    __shared__ float cv[CAP]; __shared__ int cidx[CAP];
    __shared__ int post_idx[KNN];
    __shared__ float l2s[KNN];
    __shared__ float post_w[KNN];
    __shared__ int u_idx[2 * KNN]; __shared__ float u_p[2 * KNN]; __shared__ float u_q[2 * KNN];

    if (t < KNN) post_idx[t] = 0;            // defensive: never leave garbage indices
    int n = cnt[q];
    n = (n < 0) ? 0 : ((n > CAP) ? CAP : n);
    for (int e = t; e < n; e += 256) {
        float2 c = cand[(size_t)q * CAP + e];
        cv[e] = c.x; cidx[e] = __float_as_int(c.y);
    }
    __syncthreads();

    // exact rank select of 16 smallest ((val, idx) total order; append-order invariant)
    for (int e = t; e < n; e += 256) {
        float v = cv[e]; int id = cidx[e];
        int r = 0;
        for (int i2 = 0; i2 < n; ++i2) {
            float vi = cv[i2];
            r += (vi < v) || (vi == v && cidx[i2] < id);
        }
        if (r < KNN) post_idx[r] = id;
    }
    __syncthreads();

    {   // exact f32 l2 for the selected 16 (16 threads x 8 dims each)
        int nn = t >> 4, l = t & 15;
        int idx = post_idx[nn];
        idx = (idx < 0) ? 0 : ((idx >= NDB) ? NDB - 1 : idx);   // defensive clamp
        const float* tr = Tq + q * DIM + l * 8;
        const float* xr = X + (size_t)idx * DIM + l * 8;
        float s = 0.f;
#pragma unroll
        for (int kk = 0; kk < 8; ++kk) { float df = tr[kk] - xr[kk]; s = fmaf(df, df, s); }
#pragma unroll
        for (int m = 1; m < 16; m <<= 1) s += __shfl_xor(s, m, 64);
        if (l == 0) l2s[nn] = s;
    }
    __syncthreads();

    if (t == 0) {
        float mx = -FBIG;
        for (int i = 0; i < KNN; ++i) { float v = -l2s[i] * TAU_INV; post_w[i] = v; if (v > mx) mx = v; }
        float sum = 0.f;
        for (int i = 0; i < KNN; ++i) { float e = expf(post_w[i] - mx); post_w[i] = e; sum += e; }
        float inv = 1.f / sum;
        for (int i = 0; i < KNN; ++i) post_w[i] *= inv;

        int qi = q_indices[q];
        int cnt2 = KNN;
        for (int i = 0; i < KNN; ++i) { u_idx[i] = post_idx[i]; u_q[i] = post_w[i]; u_p[i] = 0.f; }
        for (int m = 0; m < KNN; ++m) {
            int pi = pre_indices[qi * KNN + m];
            float pwm = pre_weights[qi * KNN + m];
            int f = -1;
            for (int s2 = 0; s2 < cnt2; ++s2) if (u_idx[s2] == pi) { f = s2; break; }
            if (f >= 0) u_p[f] = pwm;
            else { u_idx[cnt2] = pi; u_p[cnt2] = pwm; u_q[cnt2] = 0.f; ++cnt2; }
        }
        float Zp = 0.f, Zq = 0.f;
        for (int s2 = 0; s2 < cnt2; ++s2) { Zp += fmaxf(u_p[s2], EPSC); Zq += fmaxf(u_q[s2], EPSC); }
        float kl = 0.f;
        float izp = 1.f / Zp, izq = 1.f / Zq;
        for (int s2 = 0; s2 < cnt2; ++s2) {
            float pp = fmaxf(u_p[s2], EPSC) * izp;
            float qv = fmaxf(u_q[s2], EPSC) * izq;
            kl += pp * (logf(pp) - logf(qv));
        }
        kl_out[q] = kl;
    }
}

// ---------------- Kernel E: final reduction + outputs ----------------
__global__ void k_out(const float* __restrict__ kl, const float* __restrict__ W,
                      float* __restrict__ out) {
    int t = threadIdx.x;
    float s_kl = (t < BQ) ? kl[t] : 0.f;
    float s_w = 0.f;
    for (int i = t; i < DIM * DIM; i += 256) { float w = W[i]; s_w = fmaf(w, w, s_w); }
#pragma unroll
    for (int m = 32; m >= 1; m >>= 1) {
        s_kl += __shfl_xor(s_kl, m, 64);
        s_w += __shfl_xor(s_w, m, 64);
    }
    __shared__ float rk[4], rw[4];
    if ((t & 63) == 0) { rk[t >> 6] = s_kl; rw[t >> 6] = s_w; }
    __syncthreads();
    if (t == 0) {
        float kls = rk[0] + rk[1] + rk[2] + rk[3];
        float wss = rw[0] + rw[1] + rw[2] + rw[3];
        float knn = kls * (1.0f / BQ);
        float reg = 0.5f * wss;
        out[0] = 1.0f * knn + 1e-4f * reg;
        out[1] = 0.f;
        out[2] = knn;
    }
}

extern "C" void kernel_launch(void* const* d_in, const int* in_sizes, int n_in,
                              void* d_out, int out_size, void* d_ws, size_t ws_size,
                              hipStream_t stream) {
    const float* q_batch     = (const float*)d_in[0];
    const int*   q_indices   = (const int*)d_in[1];
    const float* X           = (const float*)d_in[2];
    const float* W           = (const float*)d_in[3];
    const int*   pre_indices = (const int*)d_in[4];
    const float* pre_weights = (const float*)d_in[5];

    char* ws = (char*)d_ws;
    float*  Tq     = (float*)(ws);                  // 128KB
    ushort* Tqb    = (ushort*)(ws + 131072);        // 64KB
    float*  klv    = (float*)(ws + 196608);         // 1KB
    float*  tauv   = (float*)(ws + 197632);         // 1KB
    int*    cntv   = (int*)(ws + 198656);           // 1KB
    float*  blkmin = (float*)(ws + 262144);         // 512*256*4 = 512KB
    float2* cand   = (float2*)(ws + 2097152);       // 256*4096*8 = 8MB

    k_tq<<<dim3(BQ), dim3(DIM), 0, stream>>>(q_batch, W, Tq, Tqb);
    k_pass<<<dim3(GRID), dim3(512), 0, stream>>>(0, Tqb, X, blkmin, tauv, cand, cntv);
    k_tau<<<dim3(BQ), dim3(64), 0, stream>>>(blkmin, tauv, cntv);
    k_pass<<<dim3(GRID), dim3(512), 0, stream>>>(1, Tqb, X, blkmin, tauv, cand, cntv);
    k_sel<<<dim3(BQ), dim3(256), 0, stream>>>(cand, cntv, Tq, X,
                                              q_indices, pre_indices, pre_weights, klv);
    k_out<<<dim3(1), dim3(256), 0, stream>>>(klv, W, (float*)d_out);
}

// Round 11
// 93.608 us; speedup vs baseline: 1.3232x; 1.0320x over previous
//
#include <hip/hip_runtime.h>
#include <math.h>

#define KNN 16
#define DIM 128
#define BQ 256
#define NDB 100000
#define GRID 512                 // k_pass blocks (exactly 2 per CU)
#define RPP 32                   // rows per phase-chunk
#define NCHUNK 3125              // 100000 / 32, exact
#define LONGB 53                 // NCHUNK - 6*GRID: blocks with 7 phases
#define XB_STR 136               // ushorts per LDS B-row (128 + 8 pad)
#define CAP 4096                 // per-query candidate capacity
#define MREG 8                   // GRID / 64
#define TAU_INV 10.0f
#define EPSC 1e-8f
#define FBIG 3.402823e38f

typedef float f32x4 __attribute__((ext_vector_type(4)));
typedef __bf16 bf16x8 __attribute__((ext_vector_type(8)));
typedef unsigned short ushort;
typedef ushort ushort8 __attribute__((ext_vector_type(8)));

__device__ __forceinline__ ushort f32_to_bf16_rne(float v) {
    unsigned bits = __float_as_uint(v);
    return (ushort)((bits + 0x7FFFu + ((bits >> 16) & 1u)) >> 16);
}

// ---------------- Kernel A: Tq = q_batch @ W (f32 + bf16 copies) ----------------
__global__ void k_tq(const float* __restrict__ qb, const float* __restrict__ W,
                     float* __restrict__ Tq, ushort* __restrict__ Tqb) {
    int b = blockIdx.x, c = threadIdx.x;   // 128 threads
    __shared__ float qs[DIM];
    qs[c] = qb[b * DIM + c];
    __syncthreads();
    float acc = 0.f;
#pragma unroll 8
    for (int k = 0; k < DIM; ++k) acc = fmaf(qs[k], W[k * DIM + c], acc);
    Tq[b * DIM + c] = acc;
    Tqb[b * DIM + c] = f32_to_bf16_rne(acc);
}

// ---------------- Kernel B0: min pass. Converts X->bf16 once (caches Xbf + xsq), ----
// tracks per-(block,query) min, writes blkmin_t[q][bid] (transposed for k_tau).
__global__ __launch_bounds__(512, 4)
void k_pass0(const ushort* __restrict__ Tqb, const float* __restrict__ X,
             ushort* __restrict__ Xbf, float* __restrict__ xsqg,
             float* __restrict__ blkmin_t) {
    __shared__ ushort xb[2][RPP * XB_STR];
    __shared__ float xsq_lds[2][RPP];
    const int t = threadIdx.x;
    const int w = t >> 6;          // wave 0..7 -> queries [32w, 32w+32)
    const int lane = t & 63;
    const int la = lane >> 4;
    const int lb = lane & 15;
    const int sr = t >> 4;         // staged row 0..31
    const int sc = t & 15;         // staged 8-dim chunk 0..15
    const int bid = blockIdx.x;
    const int nph = (bid < LONGB) ? 7 : 6;

    bf16x8 afr[2][4];              // 32 queries x K=128 = 32 VGPRs, resident
#pragma unroll
    for (int mt = 0; mt < 2; ++mt)
#pragma unroll
        for (int ks = 0; ks < 4; ++ks)
            afr[mt][ks] = *reinterpret_cast<const bf16x8*>(
                Tqb + (size_t)(w * 32 + mt * 16 + lb) * DIM + ks * 32 + la * 8);

    {   // prolog: stage chunk 0 (f32 -> bf16 + xsq), cache to global
        const int rbase = bid * RPP;
        const float4* src = reinterpret_cast<const float4*>(X + (size_t)(rbase + sr) * DIM + sc * 8);
        float4 v0 = src[0], v1 = src[1];
        ushort8 o;
        o[0]=f32_to_bf16_rne(v0.x); o[1]=f32_to_bf16_rne(v0.y); o[2]=f32_to_bf16_rne(v0.z); o[3]=f32_to_bf16_rne(v0.w);
        o[4]=f32_to_bf16_rne(v1.x); o[5]=f32_to_bf16_rne(v1.y); o[6]=f32_to_bf16_rne(v1.z); o[7]=f32_to_bf16_rne(v1.w);
        *reinterpret_cast<ushort8*>(&xb[0][sr * XB_STR + sc * 8]) = o;
        *reinterpret_cast<ushort8*>(Xbf + (size_t)(rbase + sr) * DIM + sc * 8) = o;
        float s = v0.x*v0.x + v0.y*v0.y + v0.z*v0.z + v0.w*v0.w
                + v1.x*v1.x + v1.y*v1.y + v1.z*v1.z + v1.w*v1.w;
        s += __shfl_xor(s, 1, 16); s += __shfl_xor(s, 2, 16);
        s += __shfl_xor(s, 4, 16); s += __shfl_xor(s, 8, 16);
        if (sc == 0) { xsq_lds[0][sr] = s; xsqg[rbase + sr] = s; }
    }
    asm volatile("s_waitcnt lgkmcnt(0)" ::: "memory");
    __builtin_amdgcn_s_barrier();

    float runmin[2][4];
#pragma unroll
    for (int mt = 0; mt < 2; ++mt)
#pragma unroll
        for (int r = 0; r < 4; ++r) runmin[mt][r] = FBIG;

#pragma unroll 1
    for (int p = 0; p < nph; ++p) {
        const int cur = p & 1, nxt = cur ^ 1;
        const int rbase = (bid + (p << 9)) << 5;
        const int rb2 = (bid + ((p + 1) << 9)) << 5;
        float4 q0, q1;
        if (p + 1 < nph) {
            const float4* s2 = reinterpret_cast<const float4*>(X + (size_t)(rb2 + sr) * DIM + sc * 8);
            q0 = s2[0]; q1 = s2[1];
        }

#pragma unroll
        for (int nt = 0; nt < 2; ++nt) {
            const int row = nt * 16 + lb;
            bf16x8 bfr[4];
#pragma unroll
            for (int ks = 0; ks < 4; ++ks)
                bfr[ks] = *reinterpret_cast<const bf16x8*>(
                    &xb[cur][row * XB_STR + ks * 32 + la * 8]);
            const float xs = xsq_lds[cur][row];
#pragma unroll
            for (int mt = 0; mt < 2; ++mt) {
                f32x4 acc = {0.f, 0.f, 0.f, 0.f};
#pragma unroll
                for (int ks = 0; ks < 4; ++ks)
                    acc = __builtin_amdgcn_mfma_f32_16x16x32_bf16(afr[mt][ks], bfr[ks], acc, 0, 0, 0);
#pragma unroll
                for (int r = 0; r < 4; ++r) {
                    float v = fmaf(-2.f, acc[r], xs);
                    runmin[mt][r] = fminf(runmin[mt][r], v);
                }
            }
        }

        if (p + 1 < nph) {   // write-late staging + global bf16/xsq cache
            ushort8 o;
            o[0]=f32_to_bf16_rne(q0.x); o[1]=f32_to_bf16_rne(q0.y); o[2]=f32_to_bf16_rne(q0.z); o[3]=f32_to_bf16_rne(q0.w);
            o[4]=f32_to_bf16_rne(q1.x); o[5]=f32_to_bf16_rne(q1.y); o[6]=f32_to_bf16_rne(q1.z); o[7]=f32_to_bf16_rne(q1.w);
            *reinterpret_cast<ushort8*>(&xb[nxt][sr * XB_STR + sc * 8]) = o;
            *reinterpret_cast<ushort8*>(Xbf + (size_t)(rb2 + sr) * DIM + sc * 8) = o;
            float s = q0.x*q0.x + q0.y*q0.y + q0.z*q0.z + q0.w*q0.w
                    + q1.x*q1.x + q1.y*q1.y + q1.z*q1.z + q1.w*q1.w;
            s += __shfl_xor(s, 1, 16); s += __shfl_xor(s, 2, 16);
            s += __shfl_xor(s, 4, 16); s += __shfl_xor(s, 8, 16);
            if (sc == 0) { xsq_lds[nxt][sr] = s; xsqg[rb2 + sr] = s; }
            asm volatile("s_waitcnt lgkmcnt(0)" ::: "memory");
            __builtin_amdgcn_s_barrier();
        }
    }

    // cross-lane min over 16 db cols -> blkmin_t[q][bid] (transposed)
#pragma unroll
    for (int mt = 0; mt < 2; ++mt)
#pragma unroll
        for (int r = 0; r < 4; ++r) {
            float m = runmin[mt][r];
            m = fminf(m, __shfl_xor(m, 1, 16));
            m = fminf(m, __shfl_xor(m, 2, 16));
            m = fminf(m, __shfl_xor(m, 4, 16));
            m = fminf(m, __shfl_xor(m, 8, 16));
            if (lb == 0)
                blkmin_t[(size_t)(w * 32 + mt * 16 + la * 4 + r) * GRID + bid] = m;
        }
}

// ---------------- Kernel C: per-query 16th-smallest group min (+slack) -> tau; zero counters ----
__global__ void k_tau(const float* __restrict__ blkmin_t, float* __restrict__ tau,
                      int* __restrict__ cnt) {
    const int q = blockIdx.x, lane = threadIdx.x;   // 64 threads
    float m[MREG];
#pragma unroll
    for (int k = 0; k < MREG; ++k)
        m[k] = blkmin_t[(size_t)q * GRID + lane + (k << 6)];   // coalesced
    float tv = FBIG;
    for (int e = 0; e < KNN; ++e) {
        float best = m[0];
#pragma unroll
        for (int k = 1; k < MREG; ++k) best = fminf(best, m[k]);
        float b = best;
#pragma unroll
        for (int s = 1; s < 64; s <<= 1) b = fminf(b, __shfl_xor(b, s, 64));
        tv = b;
        unsigned long long has = __ballot(best == b);
        int src = (int)__builtin_ctzll(has);
        if (lane == src) {   // remove exactly one instance
            bool done = false;
#pragma unroll
            for (int k = 0; k < MREG; ++k) {
                bool hit = !done && (m[k] == b);
                if (hit) { m[k] = FBIG; done = true; }
            }
        }
    }
    if (lane == 0) { tau[q] = tv * 1.000001f + 1e-3f; cnt[q] = 0; }
}

// ---------------- Kernel B1: filter pass from cached Xbf/xsq (bit-identical inputs) ----
__global__ __launch_bounds__(512, 4)
void k_pass1(const ushort* __restrict__ Tqb, const ushort* __restrict__ Xbf,
             const float* __restrict__ xsqg, const float* __restrict__ tau,
             float2* __restrict__ cand, int* __restrict__ cnt) {
    __shared__ ushort xb[2][RPP * XB_STR];
    __shared__ float xsq_lds[2][RPP];
    __shared__ float tau_lds[BQ];
    const int t = threadIdx.x;
    const int w = t >> 6;
    const int lane = t & 63;
    const int la = lane >> 4;
    const int lb = lane & 15;
    const int sr = t >> 4;
    const int sc = t & 15;
    const int bid = blockIdx.x;
    const int nph = (bid < LONGB) ? 7 : 6;

    bf16x8 afr[2][4];
#pragma unroll
    for (int mt = 0; mt < 2; ++mt)
#pragma unroll
        for (int ks = 0; ks < 4; ++ks)
            afr[mt][ks] = *reinterpret_cast<const bf16x8*>(
                Tqb + (size_t)(w * 32 + mt * 16 + lb) * DIM + ks * 32 + la * 8);

    if (t < BQ) tau_lds[t] = tau[t];

    {   // prolog: stage chunk 0 from bf16 cache (16B copy/thread)
        const int rbase = bid * RPP;
        ushort8 o = *reinterpret_cast<const ushort8*>(Xbf + (size_t)(rbase + sr) * DIM + sc * 8);
        *reinterpret_cast<ushort8*>(&xb[0][sr * XB_STR + sc * 8]) = o;
        if (sc == 0) xsq_lds[0][sr] = xsqg[rbase + sr];
    }
    asm volatile("s_waitcnt lgkmcnt(0)" ::: "memory");
    __builtin_amdgcn_s_barrier();

    float taur[2][4];
#pragma unroll
    for (int mt = 0; mt < 2; ++mt)
#pragma unroll
        for (int r = 0; r < 4; ++r)
            taur[mt][r] = tau_lds[w * 32 + mt * 16 + la * 4 + r];

#pragma unroll 1
    for (int p = 0; p < nph; ++p) {
        const int cur = p & 1, nxt = cur ^ 1;
        const int rbase = (bid + (p << 9)) << 5;
        const int rb2 = (bid + ((p + 1) << 9)) << 5;
        ushort8 q8; float xnext = 0.f;
        if (p + 1 < nph) {
            q8 = *reinterpret_cast<const ushort8*>(Xbf + (size_t)(rb2 + sr) * DIM + sc * 8);
            if (sc == 0) xnext = xsqg[rb2 + sr];
        }

#pragma unroll
        for (int nt = 0; nt < 2; ++nt) {
            const int row = nt * 16 + lb;
            bf16x8 bfr[4];
#pragma unroll
            for (int ks = 0; ks < 4; ++ks)
                bfr[ks] = *reinterpret_cast<const bf16x8*>(
                    &xb[cur][row * XB_STR + ks * 32 + la * 8]);
            const float xs = xsq_lds[cur][row];
            const int j = rbase + row;
#pragma unroll
            for (int mt = 0; mt < 2; ++mt) {
                f32x4 acc = {0.f, 0.f, 0.f, 0.f};
#pragma unroll
                for (int ks = 0; ks < 4; ++ks)
                    acc = __builtin_amdgcn_mfma_f32_16x16x32_bf16(afr[mt][ks], bfr[ks], acc, 0, 0, 0);
#pragma unroll
                for (int r = 0; r < 4; ++r) {
                    float v = fmaf(-2.f, acc[r], xs);
                    if (v <= taur[mt][r]) {      // rare (~40 hits/query total)
                        int qid = w * 32 + mt * 16 + la * 4 + r;
                        int pos = atomicAdd(&cnt[qid], 1);
                        if (pos < CAP)
                            cand[(size_t)qid * CAP + pos] = make_float2(v, __int_as_float(j));
                    }
                }
            }
        }

        if (p + 1 < nph) {
            *reinterpret_cast<ushort8*>(&xb[nxt][sr * XB_STR + sc * 8]) = q8;
            if (sc == 0) xsq_lds[nxt][sr] = xnext;
            asm volatile("s_waitcnt lgkmcnt(0)" ::: "memory");
            __builtin_amdgcn_s_barrier();
        }
    }
}

// ---------------- Kernel D: rank select 16 + exact l2 + softmax + union KL ----------------
__global__ __launch_bounds__(256)
void k_sel(const float2* __restrict__ cand, const int* __restrict__ cnt,
           const float* __restrict__ Tq, const float* __restrict__ X,
           const int* __restrict__ q_indices,
           const int* __restrict__ pre_indices,
           const float* __restrict__ pre_weights,
           float* __restrict__ kl_out) {
    const int q = blockIdx.x, t = threadIdx.x;
    __shared__ float cv[CAP]; __shared__ int cidx[CAP];
    __shared__ int post_idx[KNN];
    __shared__ float l2s[KNN];
    __shared__ float post_w[KNN];
    __shared__ int u_idx[2 * KNN]; __shared__ float u_p[2 * KNN]; __shared__ float u_q[2 * KNN];

    if (t < KNN) post_idx[t] = 0;            // defensive
    int n = cnt[q];
    n = (n < 0) ? 0 : ((n > CAP) ? CAP : n);
    for (int e = t; e < n; e += 256) {
        float2 c = cand[(size_t)q * CAP + e];
        cv[e] = c.x; cidx[e] = __float_as_int(c.y);
    }
    __syncthreads();

    for (int e = t; e < n; e += 256) {
        float v = cv[e]; int id = cidx[e];
        int r = 0;
        for (int i2 = 0; i2 < n; ++i2) {
            float vi = cv[i2];
            r += (vi < v) || (vi == v && cidx[i2] < id);
        }
        if (r < KNN) post_idx[r] = id;
    }
    __syncthreads();

    {   // exact f32 l2 for the selected 16
        int nn = t >> 4, l = t & 15;
        int idx = post_idx[nn];
        idx = (idx < 0) ? 0 : ((idx >= NDB) ? NDB - 1 : idx);
        const float* tr = Tq + q * DIM + l * 8;
        const float* xr = X + (size_t)idx * DIM + l * 8;
        float s = 0.f;
#pragma unroll
        for (int kk = 0; kk < 8; ++kk) { float df = tr[kk] - xr[kk]; s = fmaf(df, df, s); }
#pragma unroll
        for (int m = 1; m < 16; m <<= 1) s += __shfl_xor(s, m, 64);
        if (l == 0) l2s[nn] = s;
    }
    __syncthreads();

    if (t == 0) {
        float mx = -FBIG;
        for (int i = 0; i < KNN; ++i) { float v = -l2s[i] * TAU_INV; post_w[i] = v; if (v > mx) mx = v; }
        float sum = 0.f;
        for (int i = 0; i < KNN; ++i) { float e = expf(post_w[i] - mx); post_w[i] = e; sum += e; }
        float inv = 1.f / sum;
        for (int i = 0; i < KNN; ++i) post_w[i] *= inv;

        int qi = q_indices[q];
        int cnt2 = KNN;
        for (int i = 0; i < KNN; ++i) { u_idx[i] = post_idx[i]; u_q[i] = post_w[i]; u_p[i] = 0.f; }
        for (int m = 0; m < KNN; ++m) {
            int pi = pre_indices[qi * KNN + m];
            float pwm = pre_weights[qi * KNN + m];
            int f = -1;
            for (int s2 = 0; s2 < cnt2; ++s2) if (u_idx[s2] == pi) { f = s2; break; }
            if (f >= 0) u_p[f] = pwm;
            else { u_idx[cnt2] = pi; u_p[cnt2] = pwm; u_q[cnt2] = 0.f; ++cnt2; }
        }
        float Zp = 0.f, Zq = 0.f;
        for (int s2 = 0; s2 < cnt2; ++s2) { Zp += fmaxf(u_p[s2], EPSC); Zq += fmaxf(u_q[s2], EPSC); }
        float kl = 0.f;
        float izp = 1.f / Zp, izq = 1.f / Zq;
        for (int s2 = 0; s2 < cnt2; ++s2) {
            float pp = fmaxf(u_p[s2], EPSC) * izp;
            float qv = fmaxf(u_q[s2], EPSC) * izq;
            kl += pp * (logf(pp) - logf(qv));
        }
        kl_out[q] = kl;
    }
}

// ---------------- Kernel E: final reduction + outputs ----------------
__global__ void k_out(const float* __restrict__ kl, const float* __restrict__ W,
                      float* __restrict__ out) {
    int t = threadIdx.x;
    float s_kl = (t < BQ) ? kl[t] : 0.f;
    float s_w = 0.f;
    for (int i = t; i < DIM * DIM; i += 256) { float w = W[i]; s_w = fmaf(w, w, s_w); }
#pragma unroll
    for (int m = 32; m >= 1; m >>= 1) {
        s_kl += __shfl_xor(s_kl, m, 64);
        s_w += __shfl_xor(s_w, m, 64);
    }
    __shared__ float rk[4], rw[4];
    if ((t & 63) == 0) { rk[t >> 6] = s_kl; rw[t >> 6] = s_w; }
    __syncthreads();
    if (t == 0) {
        float kls = rk[0] + rk[1] + rk[2] + rk[3];
        float wss = rw[0] + rw[1] + rw[2] + rw[3];
        float knn = kls * (1.0f / BQ);
        float reg = 0.5f * wss;
        out[0] = 1.0f * knn + 1e-4f * reg;
        out[1] = 0.f;
        out[2] = knn;
    }
}

extern "C" void kernel_launch(void* const* d_in, const int* in_sizes, int n_in,
                              void* d_out, int out_size, void* d_ws, size_t ws_size,
                              hipStream_t stream) {
    const float* q_batch     = (const float*)d_in[0];
    const int*   q_indices   = (const int*)d_in[1];
    const float* X           = (const float*)d_in[2];
    const float* W           = (const float*)d_in[3];
    const int*   pre_indices = (const int*)d_in[4];
    const float* pre_weights = (const float*)d_in[5];

    char* ws = (char*)d_ws;
    float*  Tq      = (float*)(ws);                  // 128KB
    ushort* Tqb     = (ushort*)(ws + 131072);        // 64KB
    float*  klv     = (float*)(ws + 196608);         // 1KB
    float*  tauv    = (float*)(ws + 197632);         // 1KB
    int*    cntv    = (int*)(ws + 198656);           // 1KB
    float*  xsqg    = (float*)(ws + 262144);         // 400KB
    float*  blkmint = (float*)(ws + 786432);         // 256*512*4 = 512KB
    ushort* Xbf     = (ushort*)(ws + 1441792);       // 100000*128*2 = 25.6MB
    float2* cand    = (float2*)(ws + 28311552);      // 256*4096*8 = 8MB

    k_tq<<<dim3(BQ), dim3(DIM), 0, stream>>>(q_batch, W, Tq, Tqb);
    k_pass0<<<dim3(GRID), dim3(512), 0, stream>>>(Tqb, X, Xbf, xsqg, blkmint);
    k_tau<<<dim3(BQ), dim3(64), 0, stream>>>(blkmint, tauv, cntv);
    k_pass1<<<dim3(GRID), dim3(512), 0, stream>>>(Tqb, Xbf, xsqg, tauv, cand, cntv);
    k_sel<<<dim3(BQ), dim3(256), 0, stream>>>(cand, cntv, Tq, X,
                                              q_indices, pre_indices, pre_weights, klv);
    k_out<<<dim3(1), dim3(256), 0, stream>>>(klv, W, (float*)d_out);
}